// Round 6
// baseline (66.286 us; speedup 1.0000x reference)
//
#include <hip/hip_runtime.h>

// Problem constants (fixed by setup_inputs): N=65536 tokens, K=8, E=64 experts.
#define TOTAL   524288            // N*K flattened assignments
#define NEXP    64
#define TOPK    8
#define GSIZE   256               // blocks -- exactly 1 per CU (co-resident)
#define BLOCK   1024              // threads = 16 waves -> 4 waves/SIMD
#define NWAVE   16
#define CHUNK   (TOTAL / GSIZE)   // 2048 elements per block (2 per thread)
#define ROWSPW  (GSIZE / NWAVE)   // 16 count-rows scanned per wave

// Self-validating tagged flag word: word = TAGBASE + c, c in [0, CHUNK].
// Valid iff (word - TAGBASE) <= CHUNK (unsigned). No repeated-byte poison
// pattern can forge the 0xA5B top-12-bit tag (would need x==0xA and x==0xB).
#define TAGBASE 0xA5B00000u

typedef unsigned long long ull;
typedef unsigned int uint;

// Mask of lanes whose ballot-encoded expert equals x (x in [0,64)).
__device__ __forceinline__ ull expert_mask(const ull bb[6], int x) {
    ull m = ~0ULL;
#pragma unroll
    for (int bit = 0; bit < 6; bit++)
        m &= ((x >> bit) & 1) ? bb[bit] : ~bb[bit];
    return m;
}

// Single dispatch: histogram -> publish counts row + release tagged ready flag
// -> (overlapped local ranks + LDS staging) -> wave0-only flag spin ->
// one-shot row read -> scan -> coalesced scatter.
// Signal (256 words) is separated from payload (16K words): spin traffic is
// 64x lighter than polling the payload, so it cannot congest late blocks'
// cold input reads (which set the barrier exit time).
__global__ __launch_bounds__(BLOCK) void fused_kernel(
        const float* __restrict__ scores,
        const int*   __restrict__ idx,
        uint*        __restrict__ ready,    // [GSIZE] tagged flags (no init)
        int*         __restrict__ counts,   // [GSIZE][NEXP] rows (no init)
        float*       __restrict__ out_scores,
        float*       __restrict__ out_tok,
        float*       __restrict__ out_cnt) {
    __shared__ int   wtot[NWAVE][NEXP];     // this block: per-wave expert counts
    __shared__ int   part_pre[NWAVE][NEXP]; // per-wave partial: counts in blocks < b
    __shared__ int   part_tot[NWAVE][NEXP]; // per-wave partial: global totals
    __shared__ int   exscan_pre[NEXP];      // global expert ex-scan + block prefix
    __shared__ float sc_s[CHUNK];           // block-sorted scores
    __shared__ float tk_s[CHUNK];           // block-sorted token indices (fp32)
    __shared__ int   gp_s[CHUNK];           // global position per sorted slot

    const int tid = threadIdx.x, lane = tid & 63, wave = tid >> 6, b = blockIdx.x;
    const ull lt  = (1ULL << lane) - 1ULL;
    const ull own = 1ULL << lane;

    // --- element loads (coalesced 8B each) ---
    const int2   e2 = ((const int2*)idx)[b * (CHUNK / 2) + tid];
    const float2 s2 = ((const float2*)scores)[b * (CHUNK / 2) + tid];

    // --- ballots + lane-as-expert masks (registers only) ---
    const int e0 = e2.x, e1 = e2.y;
    ull bb0[6], bb1[6];
#pragma unroll
    for (int bit = 0; bit < 6; bit++) {
        bb0[bit] = __ballot((e0 >> bit) & 1);
        bb1[bit] = __ballot((e1 >> bit) & 1);
    }
    const ull M0 = expert_mask(bb0, lane);  // lanes with slot-0 expert == lane
    const ull M1 = expert_mask(bb1, lane);  // lanes with slot-1 expert == lane
    wtot[wave][lane] = __popcll(M0) + __popcll(M1);
    __syncthreads();

    // --- publish counts row, then release-store the tagged ready flag ------
    if (wave == 0) {
        int t = 0;
#pragma unroll
        for (int w = 0; w < NWAVE; w++) t += wtot[w][lane];
        __hip_atomic_store(&counts[b * NEXP + lane], t,
                           __ATOMIC_RELAXED, __HIP_MEMORY_SCOPE_AGENT);
        if (lane == 0)  // release: drains the wave's row stores to LLC first
            __hip_atomic_store(&ready[b], TAGBASE + 1u,
                               __ATOMIC_RELEASE, __HIP_MEMORY_SCOPE_AGENT);
    }

    // --- overlapped local work: block scan + ranks + LDS staging -----------
    int t_pre_w = 0, t_blk = 0;
#pragma unroll
    for (int w = 0; w < NWAVE; w++) {
        const int c = wtot[w][lane];
        t_pre_w += (w < wave) ? c : 0;
        t_blk   += c;
    }
    int linc = t_blk;                       // 64-lane inclusive scan (per wave)
#pragma unroll
    for (int d = 1; d < 64; d <<= 1) {
        const int v = __shfl_up(linc, d, 64);
        if (lane >= d) linc += v;
    }
    const int base_local = (linc - t_blk) + t_pre_w;  // wave's local start, expert 'lane'

    const ull own0 = __shfl(M0, e0, 64);
    const ull own1 = __shfl(M1, e1, 64);
    const ull c01  = __shfl(M1, e0, 64);
    const ull c10  = __shfl(M0, e1, 64);
    const int bl0  = __shfl(base_local, e0, 64);
    const int bl1  = __shfl(base_local, e1, 64);

    // stable in-wave ranks (flat order = 2*lane + sub)
    const int rank0 = __popcll(own0 & lt) + __popcll(c01 & lt);
    const int rank1 = __popcll(c10 & (lt | own)) + __popcll(own1 & lt);

    const int f0 = b * CHUNK + 2 * tid;     // flattened assignment index (sub 0)
    const int l0 = bl0 + rank0, l1 = bl1 + rank1;    // block-local sorted slots

    sc_s[l0] = s2.x;             sc_s[l1] = s2.y;
    tk_s[l0] = (float)(f0 >> 3); tk_s[l1] = (float)((f0 + 1) >> 3);

    // --- device-wide barrier: wave 0 spins on 4 tagged flags/lane ----------
    if (wave == 0) {
        for (;;) {
            uint r[4]; int ok = 1;
#pragma unroll
            for (int j = 0; j < 4; j++)
                r[j] = __hip_atomic_load(&ready[lane * 4 + j],
                                         __ATOMIC_RELAXED, __HIP_MEMORY_SCOPE_AGENT);
#pragma unroll
            for (int j = 0; j < 4; j++)
                ok &= (r[j] - TAGBASE) <= (uint)CHUNK;
            if (__all(ok)) break;
            __builtin_amdgcn_s_sleep(2);
        }
    }
    __syncthreads();    // waves 1-15 park here with zero memory traffic

    // --- one-shot counts scan: expert = lane, 16 rows per wave -------------
    const int r0 = wave * ROWSPW;
    int pre = 0, tot = 0;
#pragma unroll
    for (int q = 0; q < ROWSPW; q++) {
        const int c = __hip_atomic_load(&counts[(r0 + q) * NEXP + lane],
                                        __ATOMIC_RELAXED, __HIP_MEMORY_SCOPE_AGENT);
        tot += c;
        pre += ((r0 + q) < b) ? c : 0;
    }
    part_pre[wave][lane] = pre;
    part_tot[wave][lane] = tot;
    __syncthreads();

    // --- wave 0: combine partials + global expert exclusive scan -----------
    if (wave == 0) {
        int p = 0, t = 0;
#pragma unroll
        for (int w = 0; w < NWAVE; w++) {
            p += part_pre[w][lane];
            t += part_tot[w][lane];
        }
        if (b == 0) out_cnt[lane] = (float)t;   // num_tokens_per_expert (fp32)
        int inc = t;
#pragma unroll
        for (int d = 1; d < 64; d <<= 1) {
            const int vv = __shfl_up(inc, d, 64);
            if (lane >= d) inc += vv;
        }
        exscan_pre[lane] = (inc - t) + p;       // exclusive scan + block prefix
    }
    __syncthreads();

    // --- global positions for this thread's two elements -------------------
    const int base_glob = exscan_pre[lane] + t_pre_w;  // wave's global start, expert 'lane'
    const int bg0 = __shfl(base_glob, e0, 64);
    const int bg1 = __shfl(base_glob, e1, 64);
    gp_s[l0] = bg0 + rank0;
    gp_s[l1] = bg1 + rank1;
    __syncthreads();

    // --- coalesced epilogue: consecutive slots -> consecutive global addrs --
#pragma unroll
    for (int r = 0; r < 2; r++) {
        const int i = tid + r * BLOCK;
        const int p = gp_s[i];
        out_scores[p] = sc_s[i];
        out_tok[p]    = tk_s[i];
    }
}

extern "C" void kernel_launch(void* const* d_in, const int* in_sizes, int n_in,
                              void* d_out, int out_size, void* d_ws, size_t ws_size,
                              hipStream_t stream) {
    const float* top_scores = (const float*)d_in[0];
    const int*   sel_idx    = (const int*)d_in[1];
    float*       out        = (float*)d_out;
    uint*        ready      = (uint*)d_ws;           // 256 tagged flags (no init)
    int*         counts     = (int*)d_ws + 256;      // 256*64 rows (no init)

    // d_out layout: [scores_sorted (TOTAL)] [token_idx_sorted (TOTAL)] [counts (NEXP)]
    float* out_scores = out;
    float* out_tok    = out + TOTAL;
    float* out_cnt    = out + 2 * TOTAL;

    fused_kernel<<<GSIZE, BLOCK, 0, stream>>>(top_scores, sel_idx, ready, counts,
                                              out_scores, out_tok, out_cnt);
}

// Round 7
// 65.061 us; speedup vs baseline: 1.0188x; 1.0188x over previous
//
#include <hip/hip_runtime.h>

// Problem constants (fixed by setup_inputs): N=65536 tokens, K=8, E=64 experts.
#define TOTAL   524288            // N*K flattened assignments
#define NEXP    64
#define TOPK    8
#define GSIZE   256               // blocks -- exactly 1 per CU (co-resident)
#define BLOCK   1024              // threads = 16 waves -> 4 waves/SIMD
#define NWAVE   16
#define CHUNK   (TOTAL / GSIZE)   // 2048 elements per block (2 per thread)
#define ROWSPW  (GSIZE / NWAVE)   // 16 count-rows scanned per wave

// Self-validating tagged count word: word = TAGBASE + c, c in [0, CHUNK].
// Valid iff (word - TAGBASE) <= CHUNK (unsigned). No repeated-byte poison
// pattern can forge the 0xA5B top-12-bit tag (would need x==0xA and x==0xB),
// and a random word hits the window with p = 2049/2^32.
#define TAGBASE 0xA5B00000u

typedef unsigned long long ull;
typedef unsigned int uint;

// Mask of lanes whose ballot-encoded expert equals x (x in [0,64)).
__device__ __forceinline__ ull expert_mask(const ull bb[6], int x) {
    ull m = ~0ULL;
#pragma unroll
    for (int bit = 0; bit < 6; bit++)
        m &= ((x >> bit) & 1) ? bb[bit] : ~bb[bit];
    return m;
}

// Single dispatch, R5 structure + 3 tail optimizations:
//  - counts-row spin loads PREFETCHED before local staging (latency overlap)
//  - cross-wave combine + expert scan done redundantly by ALL waves
//    (no wave-0 funnel, one less __syncthreads, no exscan LDS round-trip)
//  - part_pre/part_tot merged into one int2 LDS array (ds_read_b64)
__global__ __launch_bounds__(BLOCK) void fused_kernel(
        const float* __restrict__ scores,
        const int*   __restrict__ idx,
        uint*        __restrict__ counts,   // [GSIZE][NEXP] tagged rows (no init)
        float*       __restrict__ out_scores,
        float*       __restrict__ out_tok,
        float*       __restrict__ out_cnt) {
    __shared__ int   wtot[NWAVE][NEXP];     // this block: per-wave expert counts
    __shared__ int2  part[NWAVE][NEXP];     // per-wave partial: {pre, tot}
    __shared__ float sc_s[CHUNK];           // block-sorted scores
    __shared__ float tk_s[CHUNK];           // block-sorted token indices (fp32)
    __shared__ int   gp_s[CHUNK];           // global position per sorted slot

    const int tid = threadIdx.x, lane = tid & 63, wave = tid >> 6, b = blockIdx.x;
    const ull lt  = (1ULL << lane) - 1ULL;
    const ull own = 1ULL << lane;

    // --- element loads (coalesced 8B each; idx first: ballot waits only e2) ---
    const int2   e2 = ((const int2*)idx)[b * (CHUNK / 2) + tid];
    const float2 s2 = ((const float2*)scores)[b * (CHUNK / 2) + tid];

    // --- ballots + lane-as-expert masks (registers only) ---
    const int e0 = e2.x, e1 = e2.y;
    ull bb0[6], bb1[6];
#pragma unroll
    for (int bit = 0; bit < 6; bit++) {
        bb0[bit] = __ballot((e0 >> bit) & 1);
        bb1[bit] = __ballot((e1 >> bit) & 1);
    }
    const ull M0 = expert_mask(bb0, lane);  // lanes with slot-0 expert == lane
    const ull M1 = expert_mask(bb1, lane);  // lanes with slot-1 expert == lane
    wtot[wave][lane] = __popcll(M0) + __popcll(M1);
    __syncthreads();

    // --- publish this block's tagged counts row ASAP (wave 0) ---
    if (wave == 0) {
        int t = 0;
#pragma unroll
        for (int w = 0; w < NWAVE; w++) t += wtot[w][lane];
        __hip_atomic_store(&counts[b * NEXP + lane], TAGBASE + (uint)t,
                           __ATOMIC_RELAXED, __HIP_MEMORY_SCOPE_AGENT);
    }

    // --- prefetch this wave's 16 spin words (fly during local work) --------
    const int r0 = wave * ROWSPW;
    uint v[ROWSPW];
#pragma unroll
    for (int q = 0; q < ROWSPW; q++)
        v[q] = __hip_atomic_load(&counts[(r0 + q) * NEXP + lane],
                                 __ATOMIC_RELAXED, __HIP_MEMORY_SCOPE_AGENT);

    // --- overlapped local work: block scan + ranks + LDS staging -----------
    int t_pre_w = 0, t_blk = 0;
#pragma unroll
    for (int w = 0; w < NWAVE; w++) {
        const int c = wtot[w][lane];
        t_pre_w += (w < wave) ? c : 0;
        t_blk   += c;
    }
    int linc = t_blk;                       // 64-lane inclusive scan (per wave)
#pragma unroll
    for (int d = 1; d < 64; d <<= 1) {
        const int s = __shfl_up(linc, d, 64);
        if (lane >= d) linc += s;
    }
    const int base_local = (linc - t_blk) + t_pre_w;  // wave's local start, expert 'lane'

    const ull own0 = __shfl(M0, e0, 64);
    const ull own1 = __shfl(M1, e1, 64);
    const ull c01  = __shfl(M1, e0, 64);
    const ull c10  = __shfl(M0, e1, 64);
    const int bl0  = __shfl(base_local, e0, 64);
    const int bl1  = __shfl(base_local, e1, 64);

    // stable in-wave ranks (flat order = 2*lane + sub)
    const int rank0 = __popcll(own0 & lt) + __popcll(c01 & lt);
    const int rank1 = __popcll(c10 & (lt | own)) + __popcll(own1 & lt);

    const int f0 = b * CHUNK + 2 * tid;     // flattened assignment index (sub 0)
    const int l0 = bl0 + rank0, l1 = bl1 + rank1;    // block-local sorted slots

    sc_s[l0] = s2.x;             sc_s[l1] = s2.y;
    tk_s[l0] = (float)(f0 >> 3); tk_s[l1] = (float)((f0 + 1) >> 3);

    // --- validity check on prefetched words; reload only if needed ---------
    for (;;) {
        int ok = 1;
#pragma unroll
        for (int q = 0; q < ROWSPW; q++)
            ok &= (v[q] - TAGBASE) <= (uint)CHUNK;
        if (__all(ok)) break;
        __builtin_amdgcn_s_sleep(1);
#pragma unroll
        for (int q = 0; q < ROWSPW; q++)
            v[q] = __hip_atomic_load(&counts[(r0 + q) * NEXP + lane],
                                     __ATOMIC_RELAXED, __HIP_MEMORY_SCOPE_AGENT);
    }
    int pre = 0, tot = 0;
#pragma unroll
    for (int q = 0; q < ROWSPW; q++) {
        const int c = (int)(v[q] - TAGBASE);
        tot += c;
        pre += ((r0 + q) < b) ? c : 0;
    }
    part[wave][lane] = make_int2(pre, tot);
    __syncthreads();

    // --- ALL waves redundantly: combine partials + expert exclusive scan ---
    int p = 0, t = 0;
#pragma unroll
    for (int w = 0; w < NWAVE; w++) {
        const int2 pt = part[w][lane];      // ds_read_b64, 2-way conflict (free)
        p += pt.x;
        t += pt.y;
    }
    if (b == 0 && wave == 0)
        out_cnt[lane] = (float)t;           // num_tokens_per_expert (fp32)
    int inc = t;                            // 64-lane inclusive scan over experts
#pragma unroll
    for (int d = 1; d < 64; d <<= 1) {
        const int s = __shfl_up(inc, d, 64);
        if (lane >= d) inc += s;
    }
    // global start for expert 'lane' within this wave's segment
    const int base_glob = (inc - t) + p + t_pre_w;

    // --- global positions for this thread's two elements -------------------
    const int bg0 = __shfl(base_glob, e0, 64);
    const int bg1 = __shfl(base_glob, e1, 64);
    gp_s[l0] = bg0 + rank0;
    gp_s[l1] = bg1 + rank1;
    __syncthreads();

    // --- coalesced epilogue: consecutive slots -> consecutive global addrs --
#pragma unroll
    for (int r = 0; r < 2; r++) {
        const int i = tid + r * BLOCK;
        const int gp = gp_s[i];
        out_scores[gp] = sc_s[i];
        out_tok[gp]    = tk_s[i];
    }
}

extern "C" void kernel_launch(void* const* d_in, const int* in_sizes, int n_in,
                              void* d_out, int out_size, void* d_ws, size_t ws_size,
                              hipStream_t stream) {
    const float* top_scores = (const float*)d_in[0];
    const int*   sel_idx    = (const int*)d_in[1];
    float*       out        = (float*)d_out;
    uint*        counts     = (uint*)d_ws;    // 256*64 tagged words (no init needed)

    // d_out layout: [scores_sorted (TOTAL)] [token_idx_sorted (TOTAL)] [counts (NEXP)]
    float* out_scores = out;
    float* out_tok    = out + TOTAL;
    float* out_cnt    = out + 2 * TOTAL;

    fused_kernel<<<GSIZE, BLOCK, 0, stream>>>(top_scores, sel_idx, counts,
                                              out_scores, out_tok, out_cnt);
}

// Round 8
// 63.537 us; speedup vs baseline: 1.0433x; 1.0240x over previous
//
#include <hip/hip_runtime.h>

// Problem constants (fixed by setup_inputs): N=65536 tokens, K=8, E=64 experts.
#define TOTAL   524288            // N*K flattened assignments
#define NEXP    64
#define TOPK    8
#define GSIZE   256               // blocks -- exactly 1 per CU (co-resident)
#define BLOCK   512               // threads = 8 waves -> 2 waves/SIMD
#define NWAVE   8
#define CHUNK   (TOTAL / GSIZE)   // 2048 elements per block (4 per thread)
#define ROWSPW  (GSIZE / NWAVE)   // 32 count-rows scanned per wave

// Self-validating tagged count word: word = TAGBASE + c, c in [0, CHUNK].
// Valid iff (word - TAGBASE) <= CHUNK (unsigned). No repeated-byte poison
// pattern can forge the 0xA5B top-12-bit tag (would need x==0xA and x==0xB),
// and a random word hits the window with p = 2049/2^32.
#define TAGBASE 0xA5B00000u

typedef unsigned long long ull;
typedef unsigned int uint;

// Mask of lanes whose ballot-encoded expert equals x (x in [0,64)).
__device__ __forceinline__ ull expert_mask(const ull bb[6], int x) {
    ull m = ~0ULL;
#pragma unroll
    for (int bit = 0; bit < 6; bit++)
        m &= ((x >> bit) & 1) ? bb[bit] : ~bb[bit];
    return m;
}

// R5 phase structure (best: 63.4us), geometry change only:
// 512-thread blocks (8 waves), 4 elements/thread via int4/float4 (16B/lane).
// Halves the dispatch ramp (131K threads vs 262K) and barrier width.
__global__ __launch_bounds__(BLOCK) void fused_kernel(
        const float* __restrict__ scores,
        const int*   __restrict__ idx,
        uint*        __restrict__ counts,   // [GSIZE][NEXP] tagged rows (no init)
        float*       __restrict__ out_scores,
        float*       __restrict__ out_tok,
        float*       __restrict__ out_cnt) {
    __shared__ int   wtot[NWAVE][NEXP];     // this block: per-wave expert counts
    __shared__ int   part_pre[NWAVE][NEXP]; // per-wave partial: counts in blocks < b
    __shared__ int   part_tot[NWAVE][NEXP]; // per-wave partial: global totals
    __shared__ int   exscan_pre[NEXP];      // global expert ex-scan + block prefix
    __shared__ float sc_s[CHUNK];           // block-sorted scores
    __shared__ float tk_s[CHUNK];           // block-sorted token indices (fp32)
    __shared__ int   gp_s[CHUNK];           // global position per sorted slot

    const int tid = threadIdx.x, lane = tid & 63, wave = tid >> 6, b = blockIdx.x;
    const ull lt  = (1ULL << lane) - 1ULL;
    const ull own = 1ULL << lane;

    // --- element loads: one int4 + one float4 (16B/lane, fully coalesced) ---
    const int4   e4 = ((const int4*)idx)[b * (CHUNK / 4) + tid];
    const float4 s4 = ((const float4*)scores)[b * (CHUNK / 4) + tid];
    const int   es[4] = {e4.x, e4.y, e4.z, e4.w};
    const float ss[4] = {s4.x, s4.y, s4.z, s4.w};

    // --- ballots + lane-as-expert masks, one per sub-slot (registers only) --
    ull M[4];
#pragma unroll
    for (int s = 0; s < 4; s++) {
        ull bb[6];
#pragma unroll
        for (int bit = 0; bit < 6; bit++)
            bb[bit] = __ballot((es[s] >> bit) & 1);
        M[s] = expert_mask(bb, lane);       // lanes whose slot-s expert == lane
    }
    wtot[wave][lane] = __popcll(M[0]) + __popcll(M[1]) +
                       __popcll(M[2]) + __popcll(M[3]);
    __syncthreads();

    // --- publish this block's tagged counts row ASAP (wave 0) ---
    if (wave == 0) {
        int t = 0;
#pragma unroll
        for (int w = 0; w < NWAVE; w++) t += wtot[w][lane];
        __hip_atomic_store(&counts[b * NEXP + lane], TAGBASE + (uint)t,
                           __ATOMIC_RELAXED, __HIP_MEMORY_SCOPE_AGENT);
    }

    // --- overlapped local work: block scan + ranks + LDS staging -----------
    int t_pre_w = 0, t_blk = 0;
#pragma unroll
    for (int w = 0; w < NWAVE; w++) {
        const int c = wtot[w][lane];
        t_pre_w += (w < wave) ? c : 0;
        t_blk   += c;
    }
    int linc = t_blk;                       // 64-lane inclusive scan (per wave)
#pragma unroll
    for (int d = 1; d < 64; d <<= 1) {
        const int v = __shfl_up(linc, d, 64);
        if (lane >= d) linc += v;
    }
    const int base_local = (linc - t_blk) + t_pre_w;  // wave's local start, expert 'lane'

    // stable in-wave ranks; flat order = 4*lane + s.
    // Predecessors of (lane,s) in slot s': lanes < lane, plus own lane if s'<s.
    int rnk[4], l[4];
#pragma unroll
    for (int s = 0; s < 4; s++) {
        int r = 0;
#pragma unroll
        for (int sp = 0; sp < 4; sp++) {
            const ull m = __shfl(M[sp], es[s], 64);     // M[sp](expert es[s])
            r += __popcll(m & (sp < s ? (lt | own) : lt));
        }
        rnk[s] = r;
        l[s] = __shfl(base_local, es[s], 64) + r;       // block-local sorted slot
    }

    const int f0 = b * CHUNK + 4 * tid;     // flattened assignment index (sub 0)
#pragma unroll
    for (int s = 0; s < 4; s++) {
        sc_s[l[s]] = ss[s];
        tk_s[l[s]] = (float)((f0 + s) >> 3);            // /TOPK, exact in fp32
    }

    // --- spin-read this wave's 32 counts rows (lane = expert) --------------
    const int r0 = wave * ROWSPW;
    uint v[ROWSPW];
    for (;;) {
        int ok = 1;
#pragma unroll
        for (int q = 0; q < ROWSPW; q++)
            v[q] = __hip_atomic_load(&counts[(r0 + q) * NEXP + lane],
                                     __ATOMIC_RELAXED, __HIP_MEMORY_SCOPE_AGENT);
#pragma unroll
        for (int q = 0; q < ROWSPW; q++)
            ok &= (v[q] - TAGBASE) <= (uint)CHUNK;
        if (__all(ok)) break;
        __builtin_amdgcn_s_sleep(2);
    }
    int pre = 0, tot = 0;
#pragma unroll
    for (int q = 0; q < ROWSPW; q++) {
        const int c = (int)(v[q] - TAGBASE);
        tot += c;
        pre += ((r0 + q) < b) ? c : 0;
    }
    part_pre[wave][lane] = pre;
    part_tot[wave][lane] = tot;
    __syncthreads();

    // --- wave 0: combine partials + global expert exclusive scan -----------
    if (wave == 0) {
        int p = 0, t = 0;
#pragma unroll
        for (int w = 0; w < NWAVE; w++) {
            p += part_pre[w][lane];
            t += part_tot[w][lane];
        }
        if (b == 0) out_cnt[lane] = (float)t;   // num_tokens_per_expert (fp32)
        int inc = t;
#pragma unroll
        for (int d = 1; d < 64; d <<= 1) {
            const int vv = __shfl_up(inc, d, 64);
            if (lane >= d) inc += vv;
        }
        exscan_pre[lane] = (inc - t) + p;       // exclusive scan + block prefix
    }
    __syncthreads();

    // --- global positions for this thread's four elements ------------------
    const int base_glob = exscan_pre[lane] + t_pre_w;  // wave's global start, expert 'lane'
#pragma unroll
    for (int s = 0; s < 4; s++)
        gp_s[l[s]] = __shfl(base_glob, es[s], 64) + rnk[s];
    __syncthreads();

    // --- coalesced epilogue: consecutive slots -> consecutive global addrs --
#pragma unroll
    for (int r = 0; r < 4; r++) {
        const int i = tid + r * BLOCK;
        const int gp = gp_s[i];
        out_scores[gp] = sc_s[i];
        out_tok[gp]    = tk_s[i];
    }
}

extern "C" void kernel_launch(void* const* d_in, const int* in_sizes, int n_in,
                              void* d_out, int out_size, void* d_ws, size_t ws_size,
                              hipStream_t stream) {
    const float* top_scores = (const float*)d_in[0];
    const int*   sel_idx    = (const int*)d_in[1];
    float*       out        = (float*)d_out;
    uint*        counts     = (uint*)d_ws;    // 256*64 tagged words (no init needed)

    // d_out layout: [scores_sorted (TOTAL)] [token_idx_sorted (TOTAL)] [counts (NEXP)]
    float* out_scores = out;
    float* out_tok    = out + TOTAL;
    float* out_cnt    = out + 2 * TOTAL;

    fused_kernel<<<GSIZE, BLOCK, 0, stream>>>(top_scores, sel_idx, counts,
                                              out_scores, out_tok, out_cnt);
}